// Round 9
// baseline (275.643 us; speedup 1.0000x reference)
//
#include <hip/hip_runtime.h>
#include <math.h>

#define BS 16
#define DEC 100
#define IN_LEN 512
#define HID 768
#define EMB 768
#define VOCAB 32000
#define NROW (BS*DEC)   // 1600
#define NTILE_M 13      // 128-row tiles
#define NTILE_N 250     // 128-col tiles
#define KT 12           // 768/64
#define T_SHORTS 8192   // 128 rows * 64 k (bf16) — per A or B tile

using short8 = __attribute__((ext_vector_type(8))) short;
using ushort4v = __attribute__((ext_vector_type(4))) unsigned short;
using f32x4 = __attribute__((ext_vector_type(4))) float;

__device__ __forceinline__ unsigned short f2bf(float f) {
  unsigned u = __float_as_uint(f);
  u = u + 0x7FFFu + ((u >> 16) & 1u);   // RNE
  return (unsigned short)(u >> 16);
}
__device__ __forceinline__ float bf2f(unsigned short h) {
  return __uint_as_float(((unsigned)h) << 16);
}

__device__ __forceinline__ void gll16(const void* g, void* l) {
  __builtin_amdgcn_global_load_lds(
      (const __attribute__((address_space(1))) unsigned int*)g,
      (__attribute__((address_space(3))) unsigned int*)l, 16, 0, 0);
}

// ---------------- K0: venc[b,l] = dot(enc_output[b,l,:], W_gen[0:768]) --------
__global__ __launch_bounds__(256) void k0_venc(const float* __restrict__ enc_out,
                                               const float* __restrict__ Wg,
                                               float* __restrict__ venc) {
  int row = blockIdx.x * 4 + (threadIdx.x >> 6);   // 8192 rows
  int lane = threadIdx.x & 63;
  const float* p = enc_out + (size_t)row * EMB;
  float s = 0.f;
  for (int e = lane; e < EMB; e += 64) s += p[e] * Wg[e];
  for (int off = 32; off; off >>= 1) s += __shfl_xor(s, off);
  if (lane == 0) venc[row] = s;
}

// ---------------- K1: per (b,d) row: p_gen, log p_gen, attn softmax stats -----
__global__ __launch_bounds__(256) void k1_row(const float* __restrict__ attn,
                                              const float* __restrict__ x,
                                              const float* __restrict__ venc,
                                              const float* __restrict__ Wg,
                                              const float* __restrict__ bgen,
                                              float* __restrict__ pg,
                                              float* __restrict__ lp,
                                              float* __restrict__ m_a,
                                              float* __restrict__ s_a) {
  int r = blockIdx.x;              // 0..1599
  int b = r / DEC;
  int tid = threadIdx.x;
  const float* arow = attn + (size_t)r * IN_LEN;
  const float* ve = venc + b * IN_LEN;
  const float* xrow = x + (size_t)r * HID;

  float pdot = 0.f, m = -1e30f;
  for (int l = tid; l < IN_LEN; l += 256) { float a = arow[l]; pdot += a * ve[l]; m = fmaxf(m, a); }
  for (int h = tid; h < HID; h += 256) pdot += xrow[h] * Wg[HID + h];

  for (int off = 32; off; off >>= 1) pdot += __shfl_xor(pdot, off);
  for (int off = 32; off; off >>= 1) m = fmaxf(m, __shfl_xor(m, off));

  __shared__ float red[8];
  if ((tid & 63) == 0) { red[tid >> 6] = pdot; red[4 + (tid >> 6)] = m; }
  __syncthreads();
  float z = red[0] + red[1] + red[2] + red[3];
  m = fmaxf(fmaxf(red[4], red[5]), fmaxf(red[6], red[7]));

  float se = 0.f;
  for (int l = tid; l < IN_LEN; l += 256) se += expf(arow[l] - m);
  for (int off = 32; off; off >>= 1) se += __shfl_xor(se, off);
  __syncthreads();
  if ((tid & 63) == 0) red[tid >> 6] = se;
  __syncthreads();
  se = red[0] + red[1] + red[2] + red[3];

  if (tid == 0) {
    z += bgen[0];
    float p, l_p;
    if (z >= 0.f) { float e = expf(-z); p = 1.f / (1.f + e); l_p = -log1pf(e); }
    else          { float e = expf(z);  p = e / (1.f + e);   l_p = z - log1pf(e); }
    pg[r] = p; lp[r] = l_p; m_a[r] = m; s_a[r] = se;
  }
}

// ---------------- P0: pack X -> bf16 tile-linear swizzled (BK=64) -------------
// Xp[mtile][kt][r(128)][slot(8)][8]; phys slot s holds k-chunk (s ^ (r&7))
__global__ __launch_bounds__(256) void p0_pack_x(const float* __restrict__ X,
                                                 unsigned short* __restrict__ Xp) {
  int mtile = blockIdx.x, kt = blockIdx.y, tid = threadIdx.x;
  size_t base = ((size_t)(mtile * KT + kt)) * T_SHORTS;
#pragma unroll
  for (int i = 0; i < 4; i++) {
    int slot = tid + i * 256;            // 0..1023
    int r = slot >> 3, s = slot & 7;
    int row = mtile * 128 + r;
    int k0 = kt * 64 + ((s ^ (r & 7)) << 3);
    short8 v;
    if (row < NROW) {
      const float* p = X + (size_t)row * HID + k0;
#pragma unroll
      for (int j = 0; j < 8; j++) v[j] = (short)f2bf(p[j]);
    } else {
#pragma unroll
      for (int j = 0; j < 8; j++) v[j] = 0;
    }
    *(short8*)&Xp[base + (size_t)slot * 8] = v;
  }
}

// ---------------- P0: pack W -> bf16 transposed tile-linear swizzled ----------
// Wp[ntile][kt][n(128)][slot(8)][8]; phys slot s holds k-chunk (s ^ (n&7))
__global__ __launch_bounds__(256) void p0_pack_w(const float* __restrict__ W,
                                                 unsigned short* __restrict__ Wp) {
  __shared__ float ld[64][129];
  int ntile = blockIdx.x, kt = blockIdx.y, tid = threadIdx.x;
#pragma unroll
  for (int i = 0; i < 32; i++) {
    int idx = tid + i * 256;             // 0..8191 = 64 k-rows x 128 cols
    int kk = idx >> 7, nn = idx & 127;
    ld[kk][nn] = W[(size_t)(kt * 64 + kk) * VOCAB + ntile * 128 + nn];
  }
  __syncthreads();
  size_t base = ((size_t)(ntile * KT + kt)) * T_SHORTS;
#pragma unroll
  for (int i = 0; i < 4; i++) {
    int slot = tid + i * 256;            // 0..1023
    int n = slot >> 3, s = slot & 7;
    int k0 = (s ^ (n & 7)) << 3;
    short8 v;
#pragma unroll
    for (int j = 0; j < 8; j++) v[j] = (short)f2bf(ld[k0 + j][n]);
    *(short8*)&Wp[base + (size_t)slot * 8] = v;
  }
}

// ---------------- K2 v5: m97 recipe — 128x128, BK=64, single 32KB buffer ------
__global__ __launch_bounds__(256) void k2_gemm_v5(const unsigned short* __restrict__ Xp,
                                                  const unsigned short* __restrict__ Wp,
                                                  const float* __restrict__ bvocab,
                                                  float* __restrict__ out,
                                                  unsigned short* __restrict__ lbf,
                                                  float* __restrict__ part,
                                                  int use_bf) {
  __shared__ __align__(16) unsigned short sh[2 * T_SHORTS];  // A | B = 32 KB
  __shared__ float red[512];                                 // 2 KB

  // bijective XCD swizzle (m204)
  int bid = blockIdx.x;
  const int NWG = NTILE_M * NTILE_N;        // 3250
  const int q = NWG / 8, rr = NWG % 8;      // 406, 2
  int xcd = bid & 7, idx = bid >> 3;
  int wg = (xcd < rr ? xcd * (q + 1) : rr * (q + 1) + (xcd - rr) * q) + idx;
  int ntile = wg / NTILE_M, mtile = wg % NTILE_M;

  const int tid = threadIdx.x;
  const int wid = tid >> 6, lane = tid & 63;
  const int wr = wid >> 1, wc = wid & 1;
  const int l15 = lane & 15, hi = lane >> 4;

  const unsigned short* aSrc = Xp + (size_t)(mtile * KT) * T_SHORTS;
  const unsigned short* bSrc = Wp + (size_t)(ntile * KT) * T_SHORTS;
  unsigned short* shA = &sh[0];
  unsigned short* shB = &sh[T_SHORTS];

  f32x4 acc[4][4] = {};

  for (int kt = 0; kt < KT; ++kt) {
    // stage A (16KB) + B (16KB): 8 x gll16 per thread
    const unsigned short* a = aSrc + (size_t)kt * T_SHORTS;
    const unsigned short* b = bSrc + (size_t)kt * T_SHORTS;
#pragma unroll
    for (int p = 0; p < 4; p++) {
      gll16(a + (size_t)(tid + p * 256) * 8, shA + (tid + p * 256) * 8);
      gll16(b + (size_t)(tid + p * 256) * 8, shB + (tid + p * 256) * 8);
    }
    __syncthreads();

#pragma unroll
    for (int ksub = 0; ksub < 2; ksub++) {
      short8 af[4], bfr[4];
#pragma unroll
      for (int mm = 0; mm < 4; mm++) {
        int r = wr * 64 + mm * 16 + l15;
        int phys = (ksub * 4 + hi) ^ (r & 7);
        af[mm] = *(const short8*)&shA[r * 64 + phys * 8];
      }
#pragma unroll
      for (int nn = 0; nn < 4; nn++) {
        int n = wc * 64 + nn * 16 + l15;
        int phys = (ksub * 4 + hi) ^ (n & 7);
        bfr[nn] = *(const short8*)&shB[n * 64 + phys * 8];
      }
#pragma unroll
      for (int mm = 0; mm < 4; mm++)
#pragma unroll
        for (int nn = 0; nn < 4; nn++)
          acc[mm][nn] = __builtin_amdgcn_mfma_f32_16x16x32_bf16(af[mm], bfr[nn], acc[mm][nn], 0, 0, 0);
    }
    __syncthreads();
  }

  // bias (softmax must include it)
  float bb[4];
#pragma unroll
  for (int nn = 0; nn < 4; nn++) bb[nn] = bvocab[ntile * 128 + wc * 64 + nn * 16 + l15];
#pragma unroll
  for (int mm = 0; mm < 4; mm++)
#pragma unroll
    for (int nn = 0; nn < 4; nn++)
#pragma unroll
      for (int j = 0; j < 4; j++) acc[mm][nn][j] += bb[nn];

  unsigned short* ldsC = &sh[0];   // 128x128 bf16 = 32 KB (reuse, after final sync)

  if (use_bf) {
#pragma unroll
    for (int mm = 0; mm < 4; mm++) {
      int row0 = wr * 64 + mm * 16 + hi * 4;
#pragma unroll
      for (int nn = 0; nn < 4; nn++) {
        int col = wc * 64 + nn * 16 + l15;
#pragma unroll
        for (int j = 0; j < 4; j++) ldsC[(row0 + j) * 128 + col] = f2bf(acc[mm][nn][j]);
      }
    }
  } else {
#pragma unroll
    for (int mm = 0; mm < 4; mm++) {
      int row0 = mtile * 128 + wr * 64 + mm * 16 + hi * 4;
#pragma unroll
      for (int nn = 0; nn < 4; nn++) {
        int col = ntile * 128 + wc * 64 + nn * 16 + l15;
#pragma unroll
        for (int j = 0; j < 4; j++) {
          int row = row0 + j;
          if (row < NROW) out[(size_t)row * VOCAB + col] = acc[mm][nn][j];
        }
      }
    }
  }

  // per-row partial max/sumexp over this wave's 64 cols
#pragma unroll
  for (int mm = 0; mm < 4; mm++) {
#pragma unroll
    for (int j = 0; j < 4; j++) {
      float mx = fmaxf(fmaxf(acc[mm][0][j], acc[mm][1][j]),
                       fmaxf(acc[mm][2][j], acc[mm][3][j]));
      mx = fmaxf(mx, __shfl_xor(mx, 1));
      mx = fmaxf(mx, __shfl_xor(mx, 2));
      mx = fmaxf(mx, __shfl_xor(mx, 4));
      mx = fmaxf(mx, __shfl_xor(mx, 8));
      float sl = __expf(acc[mm][0][j] - mx) + __expf(acc[mm][1][j] - mx) +
                 __expf(acc[mm][2][j] - mx) + __expf(acc[mm][3][j] - mx);
      sl += __shfl_xor(sl, 1);
      sl += __shfl_xor(sl, 2);
      sl += __shfl_xor(sl, 4);
      sl += __shfl_xor(sl, 8);
      if (l15 == 0) {
        int rloc = wr * 64 + mm * 16 + hi * 4 + j;   // 0..127
        int o = (rloc * 2 + wc) * 2;
        red[o] = mx; red[o + 1] = sl;
      }
    }
  }
  __syncthreads();

  if (use_bf) {
    // 128x128 = 2048 short8-units -> 8 iterations of 256 threads
#pragma unroll
    for (int i = 0; i < 8; i++) {
      int flat = tid + i * 256;          // 0..2047
      int r = flat >> 4, c = (flat & 15) * 8;
      int grow = mtile * 128 + r;
      if (grow < NROW)
        *(short8*)&lbf[(size_t)grow * VOCAB + ntile * 128 + c] = *(const short8*)&ldsC[r * 128 + c];
    }
  }
  if (tid < 128) {
    int o0 = (tid * 2 + 0) * 2;
    int o1 = (tid * 2 + 1) * 2;
    float m0 = red[o0], s0 = red[o0 + 1];
    float m1 = red[o1], s1 = red[o1 + 1];
    float m = fmaxf(m0, m1);
    float s = s0 * __expf(m0 - m) + s1 * __expf(m1 - m);
    int grow = mtile * 128 + tid;
    if (grow < NROW) {
      part[(size_t)grow * 500 + ntile * 2]     = m;
      part[(size_t)grow * 500 + ntile * 2 + 1] = s;
    }
  }
}

// ---------------- K4 fused: coef + row write + LDS-hash dedup scatter ---------
// One block per row (exclusive ownership): no global atomics, no fences.
__global__ __launch_bounds__(512) void k4_fused(float* __restrict__ out,
                                                const unsigned short* __restrict__ lbf,
                                                const float* __restrict__ part,
                                                const float* __restrict__ lp,
                                                const float* __restrict__ attn,
                                                const int* __restrict__ enc,
                                                const float* __restrict__ pg,
                                                const float* __restrict__ m_a,
                                                const float* __restrict__ s_a) {
  int r = blockIdx.x;
  int tid = threadIdx.x;
  __shared__ float sm[8], ss[8], sc[1];
  __shared__ int   s_key[1024];
  __shared__ float s_val[1024];
  s_key[tid] = -1; s_key[tid + 512] = -1;
  s_val[tid] = 0.f; s_val[tid + 512] = 0.f;

  float m = -1e30f, s = 0.f;
  if (tid < NTILE_N) {
    m = part[(size_t)r * 500 + tid * 2];
    s = part[(size_t)r * 500 + tid * 2 + 1];
  }
  for (int off = 1; off < 64; off <<= 1) {
    float mo = __shfl_xor(m, off), so = __shfl_xor(s, off);
    float nm = fmaxf(m, mo);
    s = s * __expf(m - nm) + so * __expf(mo - nm);
    m = nm;
  }
  if ((tid & 63) == 0) { sm[tid >> 6] = m; ss[tid >> 6] = s; }
  __syncthreads();                      // also publishes s_key/s_val init
  if (tid == 0) {
    float mm_ = sm[0], ss_ = ss[0];
    for (int w = 1; w < 8; w++) {
      float nm = fmaxf(mm_, sm[w]);
      ss_ = ss_ * __expf(mm_ - nm) + ss[w] * __expf(sm[w] - nm);
      mm_ = nm;
    }
    sc[0] = lp[r] - (mm_ + __logf(ss_));
  }

  // hash-insert this thread's scatter pair (dedup via key CAS + float LDS add)
  float omp = 1.f - pg[r];
  if (omp > 0.f) {
    int b_ = r / DEC;
    float t = omp * __expf(attn[(size_t)r * IN_LEN + tid] - m_a[r]) / s_a[r];
    int v = enc[b_ * IN_LEN + tid];
    int slot = v & 1023;
    while (true) {
      int old = atomicCAS(&s_key[slot], -1, v);
      if (old == -1 || old == v) { atomicAdd(&s_val[slot], t); break; }
      slot = (slot + 1) & 1023;
    }
  }
  __syncthreads();                      // sc[0] + hash complete
  float coef = sc[0];

  const short8* src = (const short8*)(lbf + (size_t)r * VOCAB);
  float* dst = out + (size_t)r * VOCAB;
  for (int i = tid; i < VOCAB / 8; i += 512) {
    short8 v = src[i];
    float4 a, b;
    a.x = bf2f((unsigned short)v[0]) + coef; a.y = bf2f((unsigned short)v[1]) + coef;
    a.z = bf2f((unsigned short)v[2]) + coef; a.w = bf2f((unsigned short)v[3]) + coef;
    b.x = bf2f((unsigned short)v[4]) + coef; b.y = bf2f((unsigned short)v[5]) + coef;
    b.z = bf2f((unsigned short)v[6]) + coef; b.w = bf2f((unsigned short)v[7]) + coef;
    *(float4*)&dst[i * 8]     = a;
    *(float4*)&dst[i * 8 + 4] = b;
  }
  __syncthreads();                      // block-local visibility of dst writes

  // each occupied hash slot does one exclusive RMW
  for (int i = tid; i < 1024; i += 512) {
    int v = s_key[i];
    if (v >= 0) {
      float sum = s_val[i];
      float p = dst[v];
      dst[v] = logf(expf(p) + sum);
    }
  }
}

// ---------------- K4e (f32 fallback): reduce partials -> coef; out += coef ----
__global__ __launch_bounds__(256) void k4_finish(float* __restrict__ out,
                                                 const float* __restrict__ part,
                                                 const float* __restrict__ lp) {
  int r = blockIdx.x >> 1, half = blockIdx.x & 1;
  int tid = threadIdx.x;
  float m = -1e30f, s = 0.f;
  if (tid < NTILE_N) {
    m = part[(size_t)r * 500 + tid * 2];
    s = part[(size_t)r * 500 + tid * 2 + 1];
  }
  for (int off = 1; off < 64; off <<= 1) {
    float mo = __shfl_xor(m, off), so = __shfl_xor(s, off);
    float nm = fmaxf(m, mo);
    s = s * __expf(m - nm) + so * __expf(mo - nm);
    m = nm;
  }
  __shared__ float sm[4], ss[4], sc[1];
  if ((tid & 63) == 0) { sm[tid >> 6] = m; ss[tid >> 6] = s; }
  __syncthreads();
  if (tid == 0) {
    float mm_ = sm[0], ss_ = ss[0];
    for (int w = 1; w < 4; w++) {
      float nm = fmaxf(mm_, sm[w]);
      ss_ = ss_ * __expf(mm_ - nm) + ss[w] * __expf(sm[w] - nm);
      mm_ = nm;
    }
    sc[0] = lp[r] - (mm_ + __logf(ss_));
  }
  __syncthreads();
  float coef = sc[0];
  float4* p = (float4*)(out + (size_t)r * VOCAB + half * (VOCAB / 2));
  for (int i = tid; i < VOCAB / 8; i += 256) {
    float4 v = p[i];
    v.x += coef; v.y += coef; v.z += coef; v.w += coef;
    p[i] = v;
  }
}

// ---------------- K4s: standalone scatter (fallback path) ---------------------
__global__ __launch_bounds__(256) void k4_scatter(float* __restrict__ out,
                                                  const float* __restrict__ attn,
                                                  const int* __restrict__ enc,
                                                  const float* __restrict__ pg,
                                                  const float* __restrict__ m_a,
                                                  const float* __restrict__ s_a) {
  int idx = blockIdx.x * 256 + threadIdx.x;     // 819200
  int l = idx & (IN_LEN - 1);
  int r = idx >> 9;
  int b = r / DEC;
  float omp = 1.f - pg[r];
  if (omp <= 0.f) return;
  float term = omp * expf(attn[(size_t)r * IN_LEN + l] - m_a[r]) / s_a[r];
  int v = enc[b * IN_LEN + l];
  unsigned* ua = (unsigned*)(out + (size_t)r * VOCAB + v);
  unsigned old = *ua;
  while (true) {
    float f = __uint_as_float(old);
    float nf = logf(expf(f) + term);
    unsigned assumed = old;
    old = atomicCAS(ua, assumed, __float_as_uint(nf));
    if (old == assumed) break;
  }
}

// ======================= FALLBACK PATH (round-1 kernels) ======================
#define BM 128
#define BN 128
#define BK 32
__device__ __forceinline__ int swz_old(int row, int k) {
  int slot = (k >> 3) ^ ((row >> 1) & 3);
  return row * 32 + slot * 8 + (k & 7);
}

__global__ __launch_bounds__(256) void k2_gemm_old(const float* __restrict__ X,
                                                   const float* __restrict__ W,
                                                   const float* __restrict__ bvocab,
                                                   float* __restrict__ out) {
  __shared__ __align__(16) unsigned short As[BM * BK];
  __shared__ __align__(16) unsigned short Bs[BN * BK];
  const int mtile = blockIdx.x;
  const int ntile = blockIdx.y;
  const int tid = threadIdx.x;
  const int wid = tid >> 6, lane = tid & 63;
  const int wr = wid >> 1, wc = wid & 1;
  f32x4 acc[4][4] = {};
  float4 areg[4];
  float  breg[16];
  const int nl = tid & 127;
  const int kg = tid >> 7;
  {
#pragma unroll
    for (int i = 0; i < 4; i++) {
      int idx = tid + i * 256;
      int r = mtile * BM + (idx >> 3);
      if (r < NROW) areg[i] = *(const float4*)(X + (size_t)r * HID + (idx & 7) * 4);
      else areg[i] = make_float4(0.f, 0.f, 0.f, 0.f);
    }
    const float* base = W + (size_t)(kg * 16) * VOCAB + ntile * BN + nl;
#pragma unroll
    for (int i = 0; i < 16; i++) breg[i] = base[(size_t)i * VOCAB];
  }
  const int KS = HID / BK;
  for (int ks = 0; ks < KS; ++ks) {
#pragma unroll
    for (int i = 0; i < 4; i++) {
      int idx = tid + i * 256;
      int r = idx >> 3, kq = idx & 7;
      ushort4v w;
      w[0] = f2bf(areg[i].x); w[1] = f2bf(areg[i].y);
      w[2] = f2bf(areg[i].z); w[3] = f2bf(areg[i].w);
      *(ushort4v*)&As[swz_old(r, kq * 4)] = w;
    }
    {
      short8 v0, v1;
#pragma unroll
      for (int i = 0; i < 8; i++) { v0[i] = (short)f2bf(breg[i]); v1[i] = (short)f2bf(breg[8 + i]); }
      *(short8*)&Bs[swz_old(nl, kg * 16)] = v0;
      *(short8*)&Bs[swz_old(nl, kg * 16 + 8)] = v1;
    }
    __syncthreads();
    if (ks + 1 < KS) {
      const int ksn = ks + 1;
#pragma unroll
      for (int i = 0; i < 4; i++) {
        int idx = tid + i * 256;
        int r = mtile * BM + (idx >> 3);
        if (r < NROW) areg[i] = *(const float4*)(X + (size_t)r * HID + ksn * BK + (idx & 7) * 4);
        else areg[i] = make_float4(0.f, 0.f, 0.f, 0.f);
      }
      const float* base = W + (size_t)(ksn * BK + kg * 16) * VOCAB + ntile * BN + nl;
#pragma unroll
      for (int i = 0; i < 16; i++) breg[i] = base[(size_t)i * VOCAB];
    }
    {
      const int k0 = (lane >> 4) * 8;
      const int rbase = wr * 64 + (lane & 15);
      const int cbase = wc * 64 + (lane & 15);
      short8 af[4], bf[4];
#pragma unroll
      for (int mm = 0; mm < 4; mm++) af[mm] = *(const short8*)&As[swz_old(rbase + mm * 16, k0)];
#pragma unroll
      for (int nn = 0; nn < 4; nn++) bf[nn] = *(const short8*)&Bs[swz_old(cbase + nn * 16, k0)];
#pragma unroll
      for (int mm = 0; mm < 4; mm++)
#pragma unroll
        for (int nn = 0; nn < 4; nn++)
          acc[mm][nn] = __builtin_amdgcn_mfma_f32_16x16x32_bf16(af[mm], bf[nn], acc[mm][nn], 0, 0, 0);
    }
    __syncthreads();
  }
#pragma unroll
  for (int mm = 0; mm < 4; mm++) {
    int row0 = mtile * BM + wr * 64 + mm * 16 + (lane >> 4) * 4;
#pragma unroll
    for (int nn = 0; nn < 4; nn++) {
      int col = ntile * BN + wc * 64 + nn * 16 + (lane & 15);
      float bb = bvocab[col];
#pragma unroll
      for (int j = 0; j < 4; j++) {
        int row = row0 + j;
        if (row < NROW) out[(size_t)row * VOCAB + col] = acc[mm][nn][j] + bb;
      }
    }
  }
}

__global__ __launch_bounds__(256) void k3_norm(float* __restrict__ out,
                                               const float* __restrict__ lp) {
  int r = blockIdx.x;
  float4* row = reinterpret_cast<float4*>(out + (size_t)r * VOCAB);
  int tid = threadIdx.x;
  float m = -1e30f, s = 0.f;
  for (int i = tid; i < VOCAB / 4; i += 256) {
    float4 v = row[i];
    float m4 = fmaxf(fmaxf(v.x, v.y), fmaxf(v.z, v.w));
    if (m4 > m) { s *= __expf(m - m4); m = m4; }
    s += __expf(v.x - m) + __expf(v.y - m) + __expf(v.z - m) + __expf(v.w - m);
  }
  for (int off = 32; off; off >>= 1) {
    float mo = __shfl_xor(m, off), so = __shfl_xor(s, off);
    float nm = fmaxf(m, mo);
    s = s * __expf(m - nm) + so * __expf(mo - nm);
    m = nm;
  }
  __shared__ float mred[4], sred[4];
  if ((tid & 63) == 0) { mred[tid >> 6] = m; sred[tid >> 6] = s; }
  __syncthreads();
  if (tid == 0) {
    float mm = mred[0], ss = sred[0];
    for (int w = 1; w < 4; w++) {
      float mo = mred[w], so = sred[w];
      float nm = fmaxf(mm, mo);
      ss = ss * __expf(mm - nm) + so * __expf(mo - nm);
      mm = nm;
    }
    mred[0] = mm; sred[0] = ss;
  }
  __syncthreads();
  m = mred[0]; s = sred[0];
  float coef = lp[r] - (m + __logf(s));
  for (int i = tid; i < VOCAB / 4; i += 256) {
    float4 v = row[i];
    v.x += coef; v.y += coef; v.z += coef; v.w += coef;
    row[i] = v;
  }
}

// -----------------------------------------------------------------------------
extern "C" void kernel_launch(void* const* d_in, const int* in_sizes, int n_in,
                              void* d_out, int out_size, void* d_ws, size_t ws_size,
                              hipStream_t stream) {
  (void)in_sizes; (void)n_in; (void)out_size;
  const float* x       = (const float*)d_in[0];
  const float* attn    = (const float*)d_in[1];
  const int*   enc_in  = (const int*)d_in[2];
  const float* enc_out = (const float*)d_in[3];
  const float* Wv      = (const float*)d_in[4];
  const float* bv      = (const float*)d_in[5];
  const float* Wg      = (const float*)d_in[6];
  const float* bg      = (const float*)d_in[7];
  float* out = (float*)d_out;
  float* ws  = (float*)d_ws;

  // ws layout (float offsets)
  float* venc = ws;                       // 8192
  float* pg   = ws + 8192;                // 1600
  float* lp   = ws + 9792;                // 1600
  float* m_a  = ws + 11392;               // 1600
  float* s_a  = ws + 12992;               // 1600
  float* part = ws + 14592;               // 1600*500 = 800000
  unsigned short* Xp = (unsigned short*)(ws + 814592);    // 13*12*8192 shorts
  unsigned short* Wp = (unsigned short*)(ws + 1453568);   // 250*12*8192 shorts
  unsigned short* Lbf = (unsigned short*)(ws + 13741568); // 1600*32000 shorts
  const size_t NEED  = (size_t)13741568 * 4;              // ~55.0 MB
  const size_t NEED2 = NEED + (size_t)NROW * VOCAB * 2;   // ~157.4 MB

  hipLaunchKernelGGL(k0_venc, dim3(2048), dim3(256), 0, stream, enc_out, Wg, venc);
  hipLaunchKernelGGL(k1_row, dim3(NROW), dim3(256), 0, stream, attn, x, venc, Wg, bg,
                     pg, lp, m_a, s_a);

  if (ws_size >= NEED) {
    int use_bf = (ws_size >= NEED2) ? 1 : 0;
    hipLaunchKernelGGL(p0_pack_x, dim3(NTILE_M, KT), dim3(256), 0, stream, x, Xp);
    hipLaunchKernelGGL(p0_pack_w, dim3(NTILE_N, KT), dim3(256), 0, stream, Wv, Wp);
    hipLaunchKernelGGL(k2_gemm_v5, dim3(NTILE_M * NTILE_N), dim3(256), 0, stream,
                       Xp, Wp, bv, out, Lbf, part, use_bf);
    if (use_bf) {
      hipLaunchKernelGGL(k4_fused, dim3(NROW), dim3(512), 0, stream,
                         out, Lbf, part, lp, attn, enc_in, pg, m_a, s_a);
    } else {
      hipLaunchKernelGGL(k4_finish, dim3(NROW * 2), dim3(256), 0, stream, out, part, lp);
      hipLaunchKernelGGL(k4_scatter, dim3((NROW * IN_LEN) / 256), dim3(256), 0, stream,
                         out, attn, enc_in, pg, m_a, s_a);
    }
  } else {
    hipLaunchKernelGGL(k2_gemm_old, dim3(NTILE_M, 250), dim3(256), 0, stream,
                       x, Wv, bv, out);
    hipLaunchKernelGGL(k3_norm, dim3(NROW), dim3(256), 0, stream, out, lp);
    hipLaunchKernelGGL(k4_scatter, dim3((NROW * IN_LEN) / 256), dim3(256), 0, stream,
                       out, attn, enc_in, pg, m_a, s_a);
  }
}

// Round 11
// 243.356 us; speedup vs baseline: 1.1327x; 1.1327x over previous
//
#include <hip/hip_runtime.h>
#include <math.h>

#define BS 16
#define DEC 100
#define IN_LEN 512
#define HID 768
#define EMB 768
#define VOCAB 32000
#define NROW (BS*DEC)   // 1600
#define NTILE_M 13      // 128-row tiles
#define NTILE_N2 125    // 256-col tiles
#define KT2 24          // 768/32
#define A_SHORTS 4096   // 128*32
#define B_SHORTS 8192   // 256*32

using short8 = __attribute__((ext_vector_type(8))) short;
using ushort4v = __attribute__((ext_vector_type(4))) unsigned short;
using f32x4 = __attribute__((ext_vector_type(4))) float;

__device__ __forceinline__ unsigned short f2bf(float f) {
  unsigned u = __float_as_uint(f);
  u = u + 0x7FFFu + ((u >> 16) & 1u);   // RNE
  return (unsigned short)(u >> 16);
}
__device__ __forceinline__ float bf2f(unsigned short h) {
  return __uint_as_float(((unsigned)h) << 16);
}

__device__ __forceinline__ void gll16(const void* g, void* l) {
  __builtin_amdgcn_global_load_lds(
      (const __attribute__((address_space(1))) unsigned int*)g,
      (__attribute__((address_space(3))) unsigned int*)l, 16, 0, 0);
}

// ---------------- K0: venc[b,l] = dot(enc_output[b,l,:], W_gen[0:768]) --------
__global__ __launch_bounds__(256) void k0_venc(const float* __restrict__ enc_out,
                                               const float* __restrict__ Wg,
                                               float* __restrict__ venc) {
  int row = blockIdx.x * 4 + (threadIdx.x >> 6);   // 8192 rows
  int lane = threadIdx.x & 63;
  const float* p = enc_out + (size_t)row * EMB;
  float s = 0.f;
  for (int e = lane; e < EMB; e += 64) s += p[e] * Wg[e];
  for (int off = 32; off; off >>= 1) s += __shfl_xor(s, off);
  if (lane == 0) venc[row] = s;
}

// ---------------- K1: per (b,d) row: p_gen, log p_gen, attn softmax stats -----
__global__ __launch_bounds__(256) void k1_row(const float* __restrict__ attn,
                                              const float* __restrict__ x,
                                              const float* __restrict__ venc,
                                              const float* __restrict__ Wg,
                                              const float* __restrict__ bgen,
                                              float* __restrict__ pg,
                                              float* __restrict__ lp,
                                              float* __restrict__ m_a,
                                              float* __restrict__ s_a) {
  int r = blockIdx.x;              // 0..1599
  int b = r / DEC;
  int tid = threadIdx.x;
  const float* arow = attn + (size_t)r * IN_LEN;
  const float* ve = venc + b * IN_LEN;
  const float* xrow = x + (size_t)r * HID;

  float pdot = 0.f, m = -1e30f;
  for (int l = tid; l < IN_LEN; l += 256) { float a = arow[l]; pdot += a * ve[l]; m = fmaxf(m, a); }
  for (int h = tid; h < HID; h += 256) pdot += xrow[h] * Wg[HID + h];

  for (int off = 32; off; off >>= 1) pdot += __shfl_xor(pdot, off);
  for (int off = 32; off; off >>= 1) m = fmaxf(m, __shfl_xor(m, off));

  __shared__ float red[8];
  if ((tid & 63) == 0) { red[tid >> 6] = pdot; red[4 + (tid >> 6)] = m; }
  __syncthreads();
  float z = red[0] + red[1] + red[2] + red[3];
  m = fmaxf(fmaxf(red[4], red[5]), fmaxf(red[6], red[7]));

  float se = 0.f;
  for (int l = tid; l < IN_LEN; l += 256) se += expf(arow[l] - m);
  for (int off = 32; off; off >>= 1) se += __shfl_xor(se, off);
  __syncthreads();
  if ((tid & 63) == 0) red[tid >> 6] = se;
  __syncthreads();
  se = red[0] + red[1] + red[2] + red[3];

  if (tid == 0) {
    z += bgen[0];
    float p, l_p;
    if (z >= 0.f) { float e = expf(-z); p = 1.f / (1.f + e); l_p = -log1pf(e); }
    else          { float e = expf(z);  p = e / (1.f + e);   l_p = z - log1pf(e); }
    pg[r] = p; lp[r] = l_p; m_a[r] = m; s_a[r] = se;
  }
}

// ---------------- P0: pack X -> bf16 tile-linear swizzled (BK=32) -------------
// Xp[mtile][ks(24)][r(128)][slot(4)][8]; phys slot s holds k-chunk (s ^ (r&3))
__global__ __launch_bounds__(256) void p0_pack_x(const float* __restrict__ X,
                                                 unsigned short* __restrict__ Xp) {
  int mtile = blockIdx.x, ks = blockIdx.y, tid = threadIdx.x;
  size_t base = ((size_t)(mtile * KT2 + ks)) * A_SHORTS;
#pragma unroll
  for (int i = 0; i < 2; i++) {
    int slot = tid + i * 256;            // 0..511
    int r = slot >> 2, s = slot & 3;
    int row = mtile * 128 + r;
    int k0 = ks * 32 + ((s ^ (r & 3)) << 3);
    short8 v;
    if (row < NROW) {
      const float* p = X + (size_t)row * HID + k0;
#pragma unroll
      for (int j = 0; j < 8; j++) v[j] = (short)f2bf(p[j]);
    } else {
#pragma unroll
      for (int j = 0; j < 8; j++) v[j] = 0;
    }
    *(short8*)&Xp[base + (size_t)slot * 8] = v;
  }
}

// ---------------- P0: pack W -> bf16 transposed tile-linear swizzled ----------
// Wp[ntile][ks][n(256)][slot(4)][8]; phys slot s holds k-chunk (s ^ (n&3))
__global__ __launch_bounds__(256) void p0_pack_w(const float* __restrict__ W,
                                                 unsigned short* __restrict__ Wp) {
  __shared__ float ld[32][257];
  int ntile = blockIdx.x, ks = blockIdx.y, tid = threadIdx.x;
#pragma unroll
  for (int i = 0; i < 32; i++) {
    int idx = tid + i * 256;             // 0..8191 = 32 k-rows x 256 cols
    int kk = idx >> 8, nn = idx & 255;
    ld[kk][nn] = W[(size_t)(ks * 32 + kk) * VOCAB + ntile * 256 + nn];
  }
  __syncthreads();
  size_t base = ((size_t)(ntile * KT2 + ks)) * B_SHORTS;
#pragma unroll
  for (int i = 0; i < 4; i++) {
    int slot = tid + i * 256;            // 0..1023
    int n = slot >> 2, s = slot & 3;
    int k0 = (s ^ (n & 3)) << 3;
    short8 v;
#pragma unroll
    for (int j = 0; j < 8; j++) v[j] = (short)f2bf(ld[k0 + j][n]);
    *(short8*)&Wp[base + (size_t)slot * 8] = v;
  }
}

// ---------------- K2 v4: 128x256 tile, BK=32, 3-buf counted-vmcnt pipeline ----
__global__ __launch_bounds__(256, 2) void k2_gemm_v4(const unsigned short* __restrict__ Xp,
                                                     const unsigned short* __restrict__ Wp,
                                                     const float* __restrict__ bvocab,
                                                     float* __restrict__ out,
                                                     unsigned short* __restrict__ lbf,
                                                     float* __restrict__ part,
                                                     int use_bf) {
  __shared__ __align__(16) unsigned short sh[3][12288];  // 3 x (A 8KB | B 16KB) = 72KB

  // bijective XCD swizzle (m204)
  int bid = blockIdx.x;
  const int NWG = NTILE_M * NTILE_N2;       // 1625
  const int q = NWG / 8, rr = NWG % 8;      // 203, 1
  int xcd = bid & 7, idx = bid >> 3;
  int wg = (xcd < rr ? xcd * (q + 1) : rr * (q + 1) + (xcd - rr) * q) + idx;
  int ntile = wg / NTILE_M, mtile = wg % NTILE_M;

  const int tid = threadIdx.x;
  const int wid = tid >> 6, lane = tid & 63;
  const int wr = wid >> 1, wc = wid & 1;
  const int l15 = lane & 15, hi = lane >> 4;
  const int phys = (hi ^ (l15 & 3)) * 8;

  const unsigned short* aSrc = Xp + (size_t)(mtile * KT2) * A_SHORTS;
  const unsigned short* bSrc = Wp + (size_t)(ntile * KT2) * B_SHORTS;

  const int aoff = (wr * 64 + l15) * 32 + phys;
  const int boff = (wc * 128 + l15) * 32 + phys;

  f32x4 acc[4][8] = {};

  // prologue: stage tiles 0 (buf0) and 1 (buf1)
#pragma unroll
  for (int t = 0; t < 2; t++) {
    const unsigned short* a = aSrc + (size_t)t * A_SHORTS;
    const unsigned short* b = bSrc + (size_t)t * B_SHORTS;
    unsigned short* dA = &sh[t][0];
    unsigned short* dB = &sh[t][4096];
    gll16(a + (size_t)tid * 8,            dA + tid * 8);
    gll16(a + (size_t)(tid + 256) * 8,    dA + (tid + 256) * 8);
#pragma unroll
    for (int j2 = 0; j2 < 4; j2++)
      gll16(b + (size_t)(tid + j2 * 256) * 8, dB + (tid + j2 * 256) * 8);
  }
  asm volatile("s_waitcnt vmcnt(6)" ::: "memory");
  __builtin_amdgcn_s_barrier();
  asm volatile("" ::: "memory");

  int bcur = 0;
  for (int t = 0; t < KT2; ++t) {
    // stage tile t+2 into buffer (bcur+2)%3 — its last readers finished at t-1's barrier
    if (t + 2 < KT2) {
      int bn = bcur + 2; if (bn >= 3) bn -= 3;
      const unsigned short* a = aSrc + (size_t)(t + 2) * A_SHORTS;
      const unsigned short* b = bSrc + (size_t)(t + 2) * B_SHORTS;
      unsigned short* dA = &sh[bn][0];
      unsigned short* dB = &sh[bn][4096];
      gll16(a + (size_t)tid * 8,            dA + tid * 8);
      gll16(a + (size_t)(tid + 256) * 8,    dA + (tid + 256) * 8);
#pragma unroll
      for (int j2 = 0; j2 < 4; j2++)
        gll16(b + (size_t)(tid + j2 * 256) * 8, dB + (tid + j2 * 256) * 8);
    }
    const unsigned short* A = &sh[bcur][0];
    const unsigned short* B = &sh[bcur][4096];
    short8 af[4], bfr[8];
#pragma unroll
    for (int mm = 0; mm < 4; mm++) af[mm] = *(const short8*)&A[aoff + mm * 512];
#pragma unroll
    for (int nn = 0; nn < 8; nn++) bfr[nn] = *(const short8*)&B[boff + nn * 512];
    __builtin_amdgcn_s_setprio(1);
#pragma unroll
    for (int mm = 0; mm < 4; mm++)
#pragma unroll
      for (int nn = 0; nn < 8; nn++)
        acc[mm][nn] = __builtin_amdgcn_mfma_f32_16x16x32_bf16(af[mm], bfr[nn], acc[mm][nn], 0, 0, 0);
    __builtin_amdgcn_s_setprio(0);
    // counted drain: tile t+1's loads (issued at t-1) must be done; t+2's 6 stay in flight
    if (t < KT2 - 2) { asm volatile("s_waitcnt vmcnt(6)" ::: "memory"); }
    else             { asm volatile("s_waitcnt vmcnt(0)" ::: "memory"); }
    __builtin_amdgcn_s_barrier();
    asm volatile("" ::: "memory");
    bcur = bcur + 1; if (bcur >= 3) bcur = 0;
  }

  __syncthreads();   // full drain before LDS reuse

  // bias (softmax must include it)
  float bb[8];
#pragma unroll
  for (int nn = 0; nn < 8; nn++) bb[nn] = bvocab[ntile * 256 + wc * 128 + nn * 16 + l15];
#pragma unroll
  for (int mm = 0; mm < 4; mm++)
#pragma unroll
    for (int nn = 0; nn < 8; nn++)
#pragma unroll
      for (int j = 0; j < 4; j++) acc[mm][nn][j] += bb[nn];

  unsigned short* ldsC = &sh[0][0];            // 128x256 bf16 = 64KB
  float* red = (float*)&sh[2][8192];           // after C region (8KB free)

  if (use_bf) {
#pragma unroll
    for (int mm = 0; mm < 4; mm++) {
      int row0 = wr * 64 + mm * 16 + hi * 4;
#pragma unroll
      for (int nn = 0; nn < 8; nn++) {
        int col = wc * 128 + nn * 16 + l15;
#pragma unroll
        for (int j = 0; j < 4; j++) ldsC[(row0 + j) * 256 + col] = f2bf(acc[mm][nn][j]);
      }
    }
  } else {
#pragma unroll
    for (int mm = 0; mm < 4; mm++) {
      int row0 = mtile * 128 + wr * 64 + mm * 16 + hi * 4;
#pragma unroll
      for (int nn = 0; nn < 8; nn++) {
        int col = ntile * 256 + wc * 128 + nn * 16 + l15;
#pragma unroll
        for (int j = 0; j < 4; j++) {
          int row = row0 + j;
          if (row < NROW) out[(size_t)row * VOCAB + col] = acc[mm][nn][j];
        }
      }
    }
  }

  // per-row partial max/sumexp over this wave's 128 cols (register-only inputs)
#pragma unroll
  for (int mm = 0; mm < 4; mm++) {
#pragma unroll
    for (int j = 0; j < 4; j++) {
      float mx = acc[mm][0][j];
#pragma unroll
      for (int nn = 1; nn < 8; nn++) mx = fmaxf(mx, acc[mm][nn][j]);
      mx = fmaxf(mx, __shfl_xor(mx, 1));
      mx = fmaxf(mx, __shfl_xor(mx, 2));
      mx = fmaxf(mx, __shfl_xor(mx, 4));
      mx = fmaxf(mx, __shfl_xor(mx, 8));
      float sl = 0.f;
#pragma unroll
      for (int nn = 0; nn < 8; nn++) sl += __expf(acc[mm][nn][j] - mx);
      sl += __shfl_xor(sl, 1);
      sl += __shfl_xor(sl, 2);
      sl += __shfl_xor(sl, 4);
      sl += __shfl_xor(sl, 8);
      if (l15 == 0) {
        int rloc = wr * 64 + mm * 16 + hi * 4 + j;   // 0..127
        int o = (rloc * 2 + wc) * 2;
        red[o] = mx; red[o + 1] = sl;
      }
    }
  }
  __syncthreads();

  if (use_bf) {
    // 128 rows x 256 cols = 4096 short8-units -> 16 iterations of 256 threads
#pragma unroll
    for (int i = 0; i < 16; i++) {
      int flat = tid + i * 256;          // 0..4095
      int r = flat >> 5, c = (flat & 31) * 8;
      int grow = mtile * 128 + r;
      if (grow < NROW)
        *(short8*)&lbf[(size_t)grow * VOCAB + ntile * 256 + c] = *(const short8*)&ldsC[r * 256 + c];
    }
  }
  if (tid < 128) {
    int o0 = (tid * 2 + 0) * 2;
    int o1 = (tid * 2 + 1) * 2;
    float m0 = red[o0], s0 = red[o0 + 1];
    float m1 = red[o1], s1 = red[o1 + 1];
    float m = fmaxf(m0, m1);
    float s = s0 * __expf(m0 - m) + s1 * __expf(m1 - m);
    int grow = mtile * 128 + tid;
    if (grow < NROW) {
      part[(size_t)grow * 256 + ntile * 2]     = m;
      part[(size_t)grow * 256 + ntile * 2 + 1] = s;
    }
  }
}

// ---------------- K4 fused: 2 blocks/row — coef + half-row stream + scatter ---
// Each half-block: builds the full row hash (cheap), streams its 16000 cols,
// applies scatter RMW only for indices in its half. No global atomics/fences.
__global__ __launch_bounds__(512) void k4_fused(float* __restrict__ out,
                                                const unsigned short* __restrict__ lbf,
                                                const float* __restrict__ part,
                                                const float* __restrict__ lp,
                                                const float* __restrict__ attn,
                                                const int* __restrict__ enc,
                                                const float* __restrict__ pg,
                                                const float* __restrict__ m_a,
                                                const float* __restrict__ s_a) {
  int r = blockIdx.x >> 1;
  int half = blockIdx.x & 1;
  int tid = threadIdx.x;
  __shared__ float sm[8], ss[8], sc[1];
  __shared__ int   s_key[1024];
  __shared__ float s_val[1024];
  s_key[tid] = -1; s_key[tid + 512] = -1;
  s_val[tid] = 0.f; s_val[tid + 512] = 0.f;

  float m = -1e30f, s = 0.f;
  if (tid < NTILE_N2) {
    m = part[(size_t)r * 256 + tid * 2];
    s = part[(size_t)r * 256 + tid * 2 + 1];
  }
  for (int off = 1; off < 64; off <<= 1) {
    float mo = __shfl_xor(m, off), so = __shfl_xor(s, off);
    float nm = fmaxf(m, mo);
    s = s * __expf(m - nm) + so * __expf(mo - nm);
    m = nm;
  }
  if ((tid & 63) == 0) { sm[tid >> 6] = m; ss[tid >> 6] = s; }
  __syncthreads();                      // also publishes s_key/s_val init
  if (tid == 0) {
    float mm_ = sm[0], ss_ = ss[0];
    for (int w = 1; w < 8; w++) {
      float nm = fmaxf(mm_, sm[w]);
      ss_ = ss_ * __expf(mm_ - nm) + ss[w] * __expf(sm[w] - nm);
      mm_ = nm;
    }
    sc[0] = lp[r] - (mm_ + __logf(ss_));
  }

  // hash-insert this thread's scatter pair (dedup via key CAS + float LDS add)
  float omp = 1.f - pg[r];
  if (omp > 0.f) {
    int b_ = r / DEC;
    float t = omp * __expf(attn[(size_t)r * IN_LEN + tid] - m_a[r]) / s_a[r];
    int v = enc[b_ * IN_LEN + tid];
    int slot = v & 1023;
    while (true) {
      int old = atomicCAS(&s_key[slot], -1, v);
      if (old == -1 || old == v) { atomicAdd(&s_val[slot], t); break; }
      slot = (slot + 1) & 1023;
    }
  }
  __syncthreads();                      // sc[0] + hash complete
  float coef = sc[0];

  const int HUNITS = (VOCAB / 8) / 2;   // 2000 short8-units per half
  const short8* src = (const short8*)(lbf + (size_t)r * VOCAB) + (size_t)half * HUNITS;
  float* dst = out + (size_t)r * VOCAB;
  float* dsth = dst + (size_t)half * (VOCAB / 2);
  for (int i = tid; i < HUNITS; i += 512) {
    short8 v = src[i];
    f32x4 a, b;
    a[0] = bf2f((unsigned short)v[0]) + coef; a[1] = bf2f((unsigned short)v[1]) + coef;
    a[2] = bf2f((unsigned short)v[2]) + coef; a[3] = bf2f((unsigned short)v[3]) + coef;
    b[0] = bf2f((unsigned short)v[4]) + coef; b[1] = bf2f((unsigned short)v[5]) + coef;
    b[2] = bf2f((unsigned short)v[6]) + coef; b[3] = bf2f((unsigned short)v[7]) + coef;
    __builtin_nontemporal_store(a, (f32x4*)&dsth[i * 8]);
    __builtin_nontemporal_store(b, (f32x4*)&dsth[i * 8 + 4]);
  }
  __syncthreads();                      // block-local visibility of dst writes

  // each occupied hash slot in THIS half's column range does one exclusive RMW
  int lo = half * (VOCAB / 2), hiR = lo + (VOCAB / 2);
  for (int i = tid; i < 1024; i += 512) {
    int v = s_key[i];
    if (v >= lo && v < hiR) {
      float sum = s_val[i];
      float p = dst[v];
      dst[v] = logf(expf(p) + sum);
    }
  }
}

// ---------------- K4e (f32 fallback): reduce partials -> coef; out += coef ----
__global__ __launch_bounds__(256) void k4_finish(float* __restrict__ out,
                                                 const float* __restrict__ part,
                                                 const float* __restrict__ lp) {
  int r = blockIdx.x >> 1, half = blockIdx.x & 1;
  int tid = threadIdx.x;
  float m = -1e30f, s = 0.f;
  if (tid < NTILE_N2) {
    m = part[(size_t)r * 256 + tid * 2];
    s = part[(size_t)r * 256 + tid * 2 + 1];
  }
  for (int off = 1; off < 64; off <<= 1) {
    float mo = __shfl_xor(m, off), so = __shfl_xor(s, off);
    float nm = fmaxf(m, mo);
    s = s * __expf(m - nm) + so * __expf(mo - nm);
    m = nm;
  }
  __shared__ float sm[4], ss[4], sc[1];
  if ((tid & 63) == 0) { sm[tid >> 6] = m; ss[tid >> 6] = s; }
  __syncthreads();
  if (tid == 0) {
    float mm_ = sm[0], ss_ = ss[0];
    for (int w = 1; w < 4; w++) {
      float nm = fmaxf(mm_, sm[w]);
      ss_ = ss_ * __expf(mm_ - nm) + ss[w] * __expf(sm[w] - nm);
      mm_ = nm;
    }
    sc[0] = lp[r] - (mm_ + __logf(ss_));
  }
  __syncthreads();
  float coef = sc[0];
  float4* p = (float4*)(out + (size_t)r * VOCAB + half * (VOCAB / 2));
  for (int i = tid; i < VOCAB / 8; i += 256) {
    float4 v = p[i];
    v.x += coef; v.y += coef; v.z += coef; v.w += coef;
    p[i] = v;
  }
}

// ---------------- K4s: standalone scatter (fallback path) ---------------------
__global__ __launch_bounds__(256) void k4_scatter(float* __restrict__ out,
                                                  const float* __restrict__ attn,
                                                  const int* __restrict__ enc,
                                                  const float* __restrict__ pg,
                                                  const float* __restrict__ m_a,
                                                  const float* __restrict__ s_a) {
  int idx = blockIdx.x * 256 + threadIdx.x;     // 819200
  int l = idx & (IN_LEN - 1);
  int r = idx >> 9;
  int b = r / DEC;
  float omp = 1.f - pg[r];
  if (omp <= 0.f) return;
  float term = omp * expf(attn[(size_t)r * IN_LEN + l] - m_a[r]) / s_a[r];
  int v = enc[b * IN_LEN + l];
  unsigned* ua = (unsigned*)(out + (size_t)r * VOCAB + v);
  unsigned old = *ua;
  while (true) {
    float f = __uint_as_float(old);
    float nf = logf(expf(f) + term);
    unsigned assumed = old;
    old = atomicCAS(ua, assumed, __float_as_uint(nf));
    if (old == assumed) break;
  }
}

// ======================= FALLBACK PATH (round-1 kernels) ======================
#define BM 128
#define BN 128
#define BK 32
__device__ __forceinline__ int swz_old(int row, int k) {
  int slot = (k >> 3) ^ ((row >> 1) & 3);
  return row * 32 + slot * 8 + (k & 7);
}

__global__ __launch_bounds__(256) void k2_gemm_old(const float* __restrict__ X,
                                                   const float* __restrict__ W,
                                                   const float* __restrict__ bvocab,
                                                   float* __restrict__ out) {
  __shared__ __align__(16) unsigned short As[BM * BK];
  __shared__ __align__(16) unsigned short Bs[BN * BK];
  const int mtile = blockIdx.x;
  const int ntile = blockIdx.y;
  const int tid = threadIdx.x;
  const int wid = tid >> 6, lane = tid & 63;
  const int wr = wid >> 1, wc = wid & 1;
  f32x4 acc[4][4] = {};
  float4 areg[4];
  float  breg[16];
  const int nl = tid & 127;
  const int kg = tid >> 7;
  {
#pragma unroll
    for (int i = 0; i < 4; i++) {
      int idx = tid + i * 256;
      int r = mtile * BM + (idx >> 3);
      if (r < NROW) areg[i] = *(const float4*)(X + (size_t)r * HID + (idx & 7) * 4);
      else areg[i] = make_float4(0.f, 0.f, 0.f, 0.f);
    }
    const float* base = W + (size_t)(kg * 16) * VOCAB + ntile * BN + nl;
#pragma unroll
    for (int i = 0; i < 16; i++) breg[i] = base[(size_t)i * VOCAB];
  }
  const int KS = HID / BK;
  for (int ks = 0; ks < KS; ++ks) {
#pragma unroll
    for (int i = 0; i < 4; i++) {
      int idx = tid + i * 256;
      int r = idx >> 3, kq = idx & 7;
      ushort4v w;
      w[0] = f2bf(areg[i].x); w[1] = f2bf(areg[i].y);
      w[2] = f2bf(areg[i].z); w[3] = f2bf(areg[i].w);
      *(ushort4v*)&As[swz_old(r, kq * 4)] = w;
    }
    {
      short8 v0, v1;
#pragma unroll
      for (int i = 0; i < 8; i++) { v0[i] = (short)f2bf(breg[i]); v1[i] = (short)f2bf(breg[8 + i]); }
      *(short8*)&Bs[swz_old(nl, kg * 16)] = v0;
      *(short8*)&Bs[swz_old(nl, kg * 16 + 8)] = v1;
    }
    __syncthreads();
    if (ks + 1 < KS) {
      const int ksn = ks + 1;
#pragma unroll
      for (int i = 0; i < 4; i++) {
        int idx = tid + i * 256;
        int r = mtile * BM + (idx >> 3);
        if (r < NROW) areg[i] = *(const float4*)(X + (size_t)r * HID + ksn * BK + (idx & 7) * 4);
        else areg[i] = make_float4(0.f, 0.f, 0.f, 0.f);
      }
      const float* base = W + (size_t)(ksn * BK + kg * 16) * VOCAB + ntile * BN + nl;
#pragma unroll
      for (int i = 0; i < 16; i++) breg[i] = base[(size_t)i * VOCAB];
    }
    {
      const int k0 = (lane >> 4) * 8;
      const int rbase = wr * 64 + (lane & 15);
      const int cbase = wc * 64 + (lane & 15);
      short8 af[4], bf[4];
#pragma unroll
      for (int mm = 0; mm < 4; mm++) af[mm] = *(const short8*)&As[swz_old(rbase + mm * 16, k0)];
#pragma unroll
      for (int nn = 0; nn < 4; nn++) bf[nn] = *(const short8*)&Bs[swz_old(cbase + nn * 16, k0)];
#pragma unroll
      for (int mm = 0; mm < 4; mm++)
#pragma unroll
        for (int nn = 0; nn < 4; nn++)
          acc[mm][nn] = __builtin_amdgcn_mfma_f32_16x16x32_bf16(af[mm], bf[nn], acc[mm][nn], 0, 0, 0);
    }
    __syncthreads();
  }
#pragma unroll
  for (int mm = 0; mm < 4; mm++) {
    int row0 = mtile * BM + wr * 64 + mm * 16 + (lane >> 4) * 4;
#pragma unroll
    for (int nn = 0; nn < 4; nn++) {
      int col = ntile * BN + wc * 64 + nn * 16 + (lane & 15);
      float bb = bvocab[col];
#pragma unroll
      for (int j = 0; j < 4; j++) {
        int row = row0 + j;
        if (row < NROW) out[(size_t)row * VOCAB + col] = acc[mm][nn][j] + bb;
      }
    }
  }
}

__global__ __launch_bounds__(256) void k3_norm(float* __restrict__ out,
                                               const float* __restrict__ lp) {
  int r = blockIdx.x;
  float4* row = reinterpret_cast<float4*>(out + (size_t)r * VOCAB);
  int tid = threadIdx.x;
  float m = -1e30f, s = 0.f;
  for (int i = tid; i < VOCAB / 4; i += 256) {
    float4 v = row[i];
    float m4 = fmaxf(fmaxf(v.x, v.y), fmaxf(v.z, v.w));
    if (m4 > m) { s *= __expf(m - m4); m = m4; }
    s += __expf(v.x - m) + __expf(v.y - m) + __expf(v.z - m) + __expf(v.w - m);
  }
  for (int off = 32; off; off >>= 1) {
    float mo = __shfl_xor(m, off), so = __shfl_xor(s, off);
    float nm = fmaxf(m, mo);
    s = s * __expf(m - nm) + so * __expf(mo - nm);
    m = nm;
  }
  __shared__ float mred[4], sred[4];
  if ((tid & 63) == 0) { mred[tid >> 6] = m; sred[tid >> 6] = s; }
  __syncthreads();
  if (tid == 0) {
    float mm = mred[0], ss = sred[0];
    for (int w = 1; w < 4; w++) {
      float mo = mred[w], so = sred[w];
      float nm = fmaxf(mm, mo);
      ss = ss * __expf(mm - nm) + so * __expf(mo - nm);
      mm = nm;
    }
    mred[0] = mm; sred[0] = ss;
  }
  __syncthreads();
  m = mred[0]; s = sred[0];
  float coef = lp[r] - (m + __logf(s));
  for (int i = tid; i < VOCAB / 4; i += 256) {
    float4 v = row[i];
    v.x += coef; v.y += coef; v.z += coef; v.w += coef;
    row[i] = v;
  }
}

// -----------------------------------------------------------------------------
extern "C" void kernel_launch(void* const* d_in, const int* in_sizes, int n_in,
                              void* d_out, int out_size, void* d_ws, size_t ws_size,
                              hipStream_t stream) {
  (void)in_sizes; (void)n_in; (void)out_size;
  const float* x       = (const float*)d_in[0];
  const float* attn    = (const float*)d_in[1];
  const int*   enc_in  = (const int*)d_in[2];
  const float* enc_out = (const float*)d_in[3];
  const float* Wv      = (const float*)d_in[4];
  const float* bv      = (const float*)d_in[5];
  const float* Wg      = (const float*)d_in[6];
  const float* bg      = (const float*)d_in[7];
  float* out = (float*)d_out;
  float* ws  = (float*)d_ws;

  // ws layout (float offsets)
  float* venc = ws;                       // 8192
  float* pg   = ws + 8192;                // 1600
  float* lp   = ws + 9792;                // 1600
  float* m_a  = ws + 11392;               // 1600
  float* s_a  = ws + 12992;               // 1600
  float* part = ws + 14592;               // 1600*256 = 409600 (<=800000 reserved)
  unsigned short* Xp = (unsigned short*)(ws + 814592);    // 13*24*4096 shorts
  unsigned short* Wp = (unsigned short*)(ws + 1453568);   // 125*24*8192 shorts
  unsigned short* Lbf = (unsigned short*)(ws + 13741568); // 1600*32000 shorts
  const size_t NEED  = (size_t)13741568 * 4;              // ~55.0 MB
  const size_t NEED2 = NEED + (size_t)NROW * VOCAB * 2;   // ~157.4 MB

  hipLaunchKernelGGL(k0_venc, dim3(2048), dim3(256), 0, stream, enc_out, Wg, venc);
  hipLaunchKernelGGL(k1_row, dim3(NROW), dim3(256), 0, stream, attn, x, venc, Wg, bg,
                     pg, lp, m_a, s_a);

  if (ws_size >= NEED) {
    int use_bf = (ws_size >= NEED2) ? 1 : 0;
    hipLaunchKernelGGL(p0_pack_x, dim3(NTILE_M, KT2), dim3(256), 0, stream, x, Xp);
    hipLaunchKernelGGL(p0_pack_w, dim3(NTILE_N2, KT2), dim3(256), 0, stream, Wv, Wp);
    hipLaunchKernelGGL(k2_gemm_v4, dim3(NTILE_M * NTILE_N2), dim3(256), 0, stream,
                       Xp, Wp, bv, out, Lbf, part, use_bf);
    if (use_bf) {
      hipLaunchKernelGGL(k4_fused, dim3(NROW * 2), dim3(512), 0, stream,
                         out, Lbf, part, lp, attn, enc_in, pg, m_a, s_a);
    } else {
      hipLaunchKernelGGL(k4_finish, dim3(NROW * 2), dim3(256), 0, stream, out, part, lp);
      hipLaunchKernelGGL(k4_scatter, dim3((NROW * IN_LEN) / 256), dim3(256), 0, stream,
                         out, attn, enc_in, pg, m_a, s_a);
    }
  } else {
    hipLaunchKernelGGL(k2_gemm_old, dim3(NTILE_M, 250), dim3(256), 0, stream,
                       x, Wv, bv, out);
    hipLaunchKernelGGL(k3_norm, dim3(NROW), dim3(256), 0, stream, out, lp);
    hipLaunchKernelGGL(k4_scatter, dim3((NROW * IN_LEN) / 256), dim3(256), 0, stream,
                       out, attn, enc_in, pg, m_a, s_a);
  }
}

// Round 12
// 239.869 us; speedup vs baseline: 1.1491x; 1.0145x over previous
//
#include <hip/hip_runtime.h>
#include <math.h>

#define BS 16
#define DEC 100
#define IN_LEN 512
#define HID 768
#define EMB 768
#define VOCAB 32000
#define NROW (BS*DEC)   // 1600
#define NTILE_M 13      // 128-row tiles
#define NTILE_N2 125    // 256-col tiles
#define KT2 24          // 768/32
#define A_SHORTS 4096   // 8 fragsA * 512
#define B_SHORTS 8192   // 16 fragsB * 512

using short8 = __attribute__((ext_vector_type(8))) short;
using f32x4 = __attribute__((ext_vector_type(4))) float;

__device__ __forceinline__ unsigned short f2bf(float f) {
  unsigned u = __float_as_uint(f);
  u = u + 0x7FFFu + ((u >> 16) & 1u);   // RNE
  return (unsigned short)(u >> 16);
}
__device__ __forceinline__ float bf2f(unsigned short h) {
  return __uint_as_float(((unsigned)h) << 16);
}

__device__ __forceinline__ void gll16(const void* g, void* l) {
  __builtin_amdgcn_global_load_lds(
      (const __attribute__((address_space(1))) unsigned int*)g,
      (__attribute__((address_space(3))) unsigned int*)l, 16, 0, 0);
}

// ---------------- K0: venc[b,l] = dot(enc_output[b,l,:], W_gen[0:768]) --------
__global__ __launch_bounds__(256) void k0_venc(const float* __restrict__ enc_out,
                                               const float* __restrict__ Wg,
                                               float* __restrict__ venc) {
  int row = blockIdx.x * 4 + (threadIdx.x >> 6);   // 8192 rows
  int lane = threadIdx.x & 63;
  const float* p = enc_out + (size_t)row * EMB;
  float s = 0.f;
  for (int e = lane; e < EMB; e += 64) s += p[e] * Wg[e];
  for (int off = 32; off; off >>= 1) s += __shfl_xor(s, off);
  if (lane == 0) venc[row] = s;
}

// ---------------- K1: per (b,d) row: p_gen, log p_gen, attn softmax stats -----
__global__ __launch_bounds__(256) void k1_row(const float* __restrict__ attn,
                                              const float* __restrict__ x,
                                              const float* __restrict__ venc,
                                              const float* __restrict__ Wg,
                                              const float* __restrict__ bgen,
                                              float* __restrict__ pg,
                                              float* __restrict__ lp,
                                              float* __restrict__ m_a,
                                              float* __restrict__ s_a) {
  int r = blockIdx.x;              // 0..1599
  int b = r / DEC;
  int tid = threadIdx.x;
  const float* arow = attn + (size_t)r * IN_LEN;
  const float* ve = venc + b * IN_LEN;
  const float* xrow = x + (size_t)r * HID;

  float pdot = 0.f, m = -1e30f;
  for (int l = tid; l < IN_LEN; l += 256) { float a = arow[l]; pdot += a * ve[l]; m = fmaxf(m, a); }
  for (int h = tid; h < HID; h += 256) pdot += xrow[h] * Wg[HID + h];

  for (int off = 32; off; off >>= 1) pdot += __shfl_xor(pdot, off);
  for (int off = 32; off; off >>= 1) m = fmaxf(m, __shfl_xor(m, off));

  __shared__ float red[8];
  if ((tid & 63) == 0) { red[tid >> 6] = pdot; red[4 + (tid >> 6)] = m; }
  __syncthreads();
  float z = red[0] + red[1] + red[2] + red[3];
  m = fmaxf(fmaxf(red[4], red[5]), fmaxf(red[6], red[7]));

  float se = 0.f;
  for (int l = tid; l < IN_LEN; l += 256) se += expf(arow[l] - m);
  for (int off = 32; off; off >>= 1) se += __shfl_xor(se, off);
  __syncthreads();
  if ((tid & 63) == 0) red[tid >> 6] = se;
  __syncthreads();
  se = red[0] + red[1] + red[2] + red[3];

  if (tid == 0) {
    z += bgen[0];
    float p, l_p;
    if (z >= 0.f) { float e = expf(-z); p = 1.f / (1.f + e); l_p = -log1pf(e); }
    else          { float e = expf(z);  p = e / (1.f + e);   l_p = z - log1pf(e); }
    pg[r] = p; lp[r] = l_p; m_a[r] = m; s_a[r] = se;
  }
}

// ---------------- P0: pack X -> bf16 FRAG-MAJOR (BK=32) -----------------------
// Xp[mtile][ks][fragA f=wr*4+mm (8)][lane(64)][8]; lane l: row=wr*64+mm*16+(l&15),
// k = ks*32 + (l>>4)*8
__global__ __launch_bounds__(256) void p0_pack_x(const float* __restrict__ X,
                                                 unsigned short* __restrict__ Xp) {
  int mtile = blockIdx.x, ks = blockIdx.y, tid = threadIdx.x;
  size_t base = ((size_t)(mtile * KT2 + ks)) * A_SHORTS;
#pragma unroll
  for (int i = 0; i < 2; i++) {
    int u = tid + i * 256;               // 0..511
    int f = u >> 6, l = u & 63;
    int wr = f >> 2, mm = f & 3;
    int row = mtile * 128 + wr * 64 + mm * 16 + (l & 15);
    int k0 = ks * 32 + (l >> 4) * 8;
    short8 v;
    if (row < NROW) {
      const float* p = X + (size_t)row * HID + k0;
#pragma unroll
      for (int j = 0; j < 8; j++) v[j] = (short)f2bf(p[j]);
    } else {
#pragma unroll
      for (int j = 0; j < 8; j++) v[j] = 0;
    }
    *(short8*)&Xp[base + (size_t)u * 8] = v;
  }
}

// ---------------- P0: pack W -> bf16 FRAG-MAJOR transposed --------------------
// Wp[ntile][ks][fragB f(16)][lane(64)][8]
// f<8 (LDS group):   wc=f>>2, nn=f&3
// f>=8 (direct grp): wc=(f-8)>>2, nn=4+((f-8)&3)
// lane l: col=wc*128+nn*16+(l&15), k = ks*32 + (l>>4)*8
__global__ __launch_bounds__(256) void p0_pack_w(const float* __restrict__ W,
                                                 unsigned short* __restrict__ Wp) {
  __shared__ float ld[32][257];
  int ntile = blockIdx.x, ks = blockIdx.y, tid = threadIdx.x;
#pragma unroll
  for (int i = 0; i < 32; i++) {
    int idx = tid + i * 256;             // 32 k-rows x 256 cols
    int kk = idx >> 8, nn = idx & 255;
    ld[kk][nn] = W[(size_t)(ks * 32 + kk) * VOCAB + ntile * 256 + nn];
  }
  __syncthreads();
  size_t base = ((size_t)(ntile * KT2 + ks)) * B_SHORTS;
#pragma unroll
  for (int i = 0; i < 4; i++) {
    int u = tid + i * 256;               // 0..1023
    int f = u >> 6, l = u & 63;
    int wc, nn;
    if (f < 8) { wc = f >> 2; nn = f & 3; }
    else       { wc = (f - 8) >> 2; nn = 4 + ((f - 8) & 3); }
    int col = wc * 128 + nn * 16 + (l & 15);
    int k0 = (l >> 4) * 8;
    short8 v;
#pragma unroll
    for (int j = 0; j < 8; j++) v[j] = (short)f2bf(ld[k0 + j][col]);
    *(short8*)&Wp[base + (size_t)u * 8] = v;
  }
}

// ---------------- K2 v6: dual-port K-loop (LDS A+B03, direct-reg B47) ---------
__global__ __launch_bounds__(256, 2) void k2_gemm_v6(const unsigned short* __restrict__ Xp,
                                                     const unsigned short* __restrict__ Wp,
                                                     const float* __restrict__ bvocab,
                                                     float* __restrict__ out,
                                                     unsigned short* __restrict__ lbf,
                                                     float* __restrict__ part,
                                                     int use_bf) {
  // loop: bufA[2] 8KB each @ [0,8192); bufB[2] 8KB each @ [8192,16384) (shorts)
  // epilogue: ldsC 64KB @ [0,32768); red @ [32768,33792)
  __shared__ __align__(16) unsigned short sh[33792];

  // bijective XCD swizzle (m204)
  int bid = blockIdx.x;
  const int NWG = NTILE_M * NTILE_N2;       // 1625
  const int q = NWG / 8, rr = NWG % 8;      // 203, 1
  int xcd = bid & 7, idx = bid >> 3;
  int wg = (xcd < rr ? xcd * (q + 1) : rr * (q + 1) + (xcd - rr) * q) + idx;
  int ntile = wg / NTILE_M, mtile = wg % NTILE_M;

  const int tid = threadIdx.x;
  const int wid = tid >> 6, lane = tid & 63;
  const int wr = wid >> 1, wc = wid & 1;
  const int l15 = lane & 15, hi = lane >> 4;

  const unsigned short* aSrc = Xp + (size_t)(mtile * KT2) * A_SHORTS;
  const unsigned short* bSrc = Wp + (size_t)(ntile * KT2) * B_SHORTS;
  // direct-load base: frags 8..15, this wave's group (wc), lane offset
  const unsigned short* bDir = bSrc + (8 + wc * 4) * 512 + lane * 8;

  unsigned short* bufA0 = &sh[0];
  unsigned short* bufA1 = &sh[4096];
  unsigned short* bufB0 = &sh[8192];
  unsigned short* bufB1 = &sh[12288];

  const int aoff = (wr * 4) * 512 + lane * 8;   // + mm*512
  const int boff = (wc * 4) * 512 + lane * 8;   // + nn*512

  f32x4 acc[4][8] = {};
  short8 af[4], bl[4], rbA[4], rbB[4];

#define STAGE(t, dA, dB) { \
    const unsigned short* a_ = aSrc + (size_t)(t) * A_SHORTS; \
    const unsigned short* b_ = bSrc + (size_t)(t) * B_SHORTS; \
    gll16(a_ + (size_t)tid * 8,         dA + tid * 8); \
    gll16(a_ + (size_t)(tid + 256) * 8, dA + (tid + 256) * 8); \
    gll16(b_ + (size_t)tid * 8,         dB + tid * 8); \
    gll16(b_ + (size_t)(tid + 256) * 8, dB + (tid + 256) * 8); }

#define LOADDIR(dst, t) { \
    const unsigned short* p_ = bDir + (size_t)(t) * B_SHORTS; \
    _Pragma("unroll") for (int nn = 0; nn < 4; nn++) dst[nn] = *(const short8*)(p_ + nn * 512); }

#define DSREAD(bA, bB) { \
    _Pragma("unroll") for (int mm = 0; mm < 4; mm++) af[mm] = *(const short8*)&bA[aoff + mm * 512]; \
    _Pragma("unroll") for (int nn = 0; nn < 4; nn++) bl[nn] = *(const short8*)&bB[boff + nn * 512]; }

#define MFMA32(rb) { \
    _Pragma("unroll") for (int mm = 0; mm < 4; mm++) { \
      _Pragma("unroll") for (int nn = 0; nn < 4; nn++) \
        acc[mm][nn] = __builtin_amdgcn_mfma_f32_16x16x32_bf16(af[mm], bl[nn], acc[mm][nn], 0, 0, 0); \
      _Pragma("unroll") for (int nn = 0; nn < 4; nn++) \
        acc[mm][4 + nn] = __builtin_amdgcn_mfma_f32_16x16x32_bf16(af[mm], rb[nn], acc[mm][4 + nn], 0, 0, 0); } }

  // prologue: tile 0
  STAGE(0, bufA0, bufB0);
  LOADDIR(rbA, 0);
  asm volatile("s_waitcnt vmcnt(4)" ::: "memory");   // glls(0) done; rbA(0) in flight
  __builtin_amdgcn_s_barrier();
  asm volatile("" ::: "memory");

  for (int tt = 0; tt < 22; tt += 2) {
    // t = tt (even): consume buf0/rbA, stage t+1 into buf1/rbB
    STAGE(tt + 1, bufA1, bufB1);
    LOADDIR(rbB, tt + 1);
    DSREAD(bufA0, bufB0);
    __builtin_amdgcn_s_setprio(1);
    MFMA32(rbA);
    __builtin_amdgcn_s_setprio(0);
    asm volatile("s_waitcnt vmcnt(4)" ::: "memory");
    __builtin_amdgcn_s_barrier();
    asm volatile("" ::: "memory");
    // t = tt+1 (odd): consume buf1/rbB, stage t+2 into buf0/rbA
    STAGE(tt + 2, bufA0, bufB0);
    LOADDIR(rbA, tt + 2);
    DSREAD(bufA1, bufB1);
    __builtin_amdgcn_s_setprio(1);
    MFMA32(rbB);
    __builtin_amdgcn_s_setprio(0);
    asm volatile("s_waitcnt vmcnt(4)" ::: "memory");
    __builtin_amdgcn_s_barrier();
    asm volatile("" ::: "memory");
  }
  // t = 22: stage 23
  STAGE(23, bufA1, bufB1);
  LOADDIR(rbB, 23);
  DSREAD(bufA0, bufB0);
  __builtin_amdgcn_s_setprio(1);
  MFMA32(rbA);
  __builtin_amdgcn_s_setprio(0);
  asm volatile("s_waitcnt vmcnt(4)" ::: "memory");
  __builtin_amdgcn_s_barrier();
  asm volatile("" ::: "memory");
  // t = 23: no staging
  DSREAD(bufA1, bufB1);
  MFMA32(rbB);
#undef STAGE
#undef LOADDIR
#undef DSREAD
#undef MFMA32

  __syncthreads();   // full drain before LDS reuse

  // bias (softmax must include it). col layout: nn<4 -> LDS group, nn>=4 -> direct
  float bb[8];
#pragma unroll
  for (int nn = 0; nn < 8; nn++) bb[nn] = bvocab[ntile * 256 + wc * 128 + nn * 16 + l15];
#pragma unroll
  for (int mm = 0; mm < 4; mm++)
#pragma unroll
    for (int nn = 0; nn < 8; nn++)
#pragma unroll
      for (int j = 0; j < 4; j++) acc[mm][nn][j] += bb[nn];

  unsigned short* ldsC = &sh[0];               // 128x256 bf16 = 64KB
  float* red = (float*)&sh[32768];             // 512 floats

  if (use_bf) {
#pragma unroll
    for (int mm = 0; mm < 4; mm++) {
      int row0 = wr * 64 + mm * 16 + hi * 4;
#pragma unroll
      for (int nn = 0; nn < 8; nn++) {
        int col = wc * 128 + nn * 16 + l15;
#pragma unroll
        for (int j = 0; j < 4; j++) ldsC[(row0 + j) * 256 + col] = f2bf(acc[mm][nn][j]);
      }
    }
  } else {
#pragma unroll
    for (int mm = 0; mm < 4; mm++) {
      int row0 = mtile * 128 + wr * 64 + mm * 16 + hi * 4;
#pragma unroll
      for (int nn = 0; nn < 8; nn++) {
        int col = ntile * 256 + wc * 128 + nn * 16 + l15;
#pragma unroll
        for (int j = 0; j < 4; j++) {
          int row = row0 + j;
          if (row < NROW) out[(size_t)row * VOCAB + col] = acc[mm][nn][j];
        }
      }
    }
  }

  // per-row partial max/sumexp over this wave's 128 cols (register-only inputs)
#pragma unroll
  for (int mm = 0; mm < 4; mm++) {
#pragma unroll
    for (int j = 0; j < 4; j++) {
      float mx = acc[mm][0][j];
#pragma unroll
      for (int nn = 1; nn < 8; nn++) mx = fmaxf(mx, acc[mm][nn][j]);
      mx = fmaxf(mx, __shfl_xor(mx, 1));
      mx = fmaxf(mx, __shfl_xor(mx, 2));
      mx = fmaxf(mx, __shfl_xor(mx, 4));
      mx = fmaxf(mx, __shfl_xor(mx, 8));
      float sl = 0.f;
#pragma unroll
      for (int nn = 0; nn < 8; nn++) sl += __expf(acc[mm][nn][j] - mx);
      sl += __shfl_xor(sl, 1);
      sl += __shfl_xor(sl, 2);
      sl += __shfl_xor(sl, 4);
      sl += __shfl_xor(sl, 8);
      if (l15 == 0) {
        int rloc = wr * 64 + mm * 16 + hi * 4 + j;   // 0..127
        int o = (rloc * 2 + wc) * 2;
        red[o] = mx; red[o + 1] = sl;
      }
    }
  }
  __syncthreads();

  if (use_bf) {
#pragma unroll
    for (int i = 0; i < 16; i++) {
      int flat = tid + i * 256;          // 0..4095
      int r = flat >> 5, c = (flat & 31) * 8;
      int grow = mtile * 128 + r;
      if (grow < NROW)
        *(short8*)&lbf[(size_t)grow * VOCAB + ntile * 256 + c] = *(const short8*)&ldsC[r * 256 + c];
    }
  }
  if (tid < 128) {
    int o0 = (tid * 2 + 0) * 2;
    int o1 = (tid * 2 + 1) * 2;
    float m0 = red[o0], s0 = red[o0 + 1];
    float m1 = red[o1], s1 = red[o1 + 1];
    float m = fmaxf(m0, m1);
    float s = s0 * __expf(m0 - m) + s1 * __expf(m1 - m);
    int grow = mtile * 128 + tid;
    if (grow < NROW) {
      part[(size_t)grow * 256 + ntile * 2]     = m;
      part[(size_t)grow * 256 + ntile * 2 + 1] = s;
    }
  }
}

// ---------------- K4 fused: 2 blocks/row — coef + half-row stream + scatter ---
__global__ __launch_bounds__(512) void k4_fused(float* __restrict__ out,
                                                const unsigned short* __restrict__ lbf,
                                                const float* __restrict__ part,
                                                const float* __restrict__ lp,
                                                const float* __restrict__ attn,
                                                const int* __restrict__ enc,
                                                const float* __restrict__ pg,
                                                const float* __restrict__ m_a,
                                                const float* __restrict__ s_a) {
  int r = blockIdx.x >> 1;
  int half = blockIdx.x & 1;
  int tid = threadIdx.x;
  __shared__ float sm[8], ss[8], sc[1];
  __shared__ int   s_key[1024];
  __shared__ float s_val[1024];
  s_key[tid] = -1; s_key[tid + 512] = -1;
  s_val[tid] = 0.f; s_val[tid + 512] = 0.f;

  float m = -1e30f, s = 0.f;
  if (tid < NTILE_N2) {
    m = part[(size_t)r * 256 + tid * 2];
    s = part[(size_t)r * 256 + tid * 2 + 1];
  }
  for (int off = 1; off < 64; off <<= 1) {
    float mo = __shfl_xor(m, off), so = __shfl_xor(s, off);
    float nm = fmaxf(m, mo);
    s = s * __expf(m - nm) + so * __expf(mo - nm);
    m = nm;
  }
  if ((tid & 63) == 0) { sm[tid >> 6] = m; ss[tid >> 6] = s; }
  __syncthreads();                      // also publishes s_key/s_val init
  if (tid == 0) {
    float mm_ = sm[0], ss_ = ss[0];
    for (int w = 1; w < 8; w++) {
      float nm = fmaxf(mm_, sm[w]);
      ss_ = ss_ * __expf(mm_ - nm) + ss[w] * __expf(sm[w] - nm);
      mm_ = nm;
    }
    sc[0] = lp[r] - (mm_ + __logf(ss_));
  }

  // hash-insert this thread's scatter pair (dedup via key CAS + float LDS add)
  float omp = 1.f - pg[r];
  if (omp > 0.f) {
    int b_ = r / DEC;
    float t = omp * __expf(attn[(size_t)r * IN_LEN + tid] - m_a[r]) / s_a[r];
    int v = enc[b_ * IN_LEN + tid];
    int slot = v & 1023;
    while (true) {
      int old = atomicCAS(&s_key[slot], -1, v);
      if (old == -1 || old == v) { atomicAdd(&s_val[slot], t); break; }
      slot = (slot + 1) & 1023;
    }
  }
  __syncthreads();                      // sc[0] + hash complete
  float coef = sc[0];

  const int HUNITS = (VOCAB / 8) / 2;   // 2000 short8-units per half
  const short8* src = (const short8*)(lbf + (size_t)r * VOCAB) + (size_t)half * HUNITS;
  float* dst = out + (size_t)r * VOCAB;
  float* dsth = dst + (size_t)half * (VOCAB / 2);
  for (int i = tid; i < HUNITS; i += 512) {
    short8 v = src[i];
    f32x4 a, b;
    a[0] = bf2f((unsigned short)v[0]) + coef; a[1] = bf2f((unsigned short)v[1]) + coef;
    a[2] = bf2f((unsigned short)v[2]) + coef; a[3] = bf2f((unsigned short)v[3]) + coef;
    b[0] = bf2f((unsigned short)v[4]) + coef; b[1] = bf2f((unsigned short)v[5]) + coef;
    b[2] = bf2f((unsigned short)v[6]) + coef; b[3] = bf2f((unsigned short)v[7]) + coef;
    __builtin_nontemporal_store(a, (f32x4*)&dsth[i * 8]);
    __builtin_nontemporal_store(b, (f32x4*)&dsth[i * 8 + 4]);
  }
  __syncthreads();                      // block-local visibility of dst writes

  // each occupied hash slot in THIS half's column range does one exclusive RMW
  int lo = half * (VOCAB / 2), hiR = lo + (VOCAB / 2);
  for (int i = tid; i < 1024; i += 512) {
    int v = s_key[i];
    if (v >= lo && v < hiR) {
      float sum = s_val[i];
      float p = dst[v];
      dst[v] = logf(expf(p) + sum);
    }
  }
}

// ---------------- K4e (f32 fallback): reduce partials -> coef; out += coef ----
__global__ __launch_bounds__(256) void k4_finish(float* __restrict__ out,
                                                 const float* __restrict__ part,
                                                 const float* __restrict__ lp) {
  int r = blockIdx.x >> 1, half = blockIdx.x & 1;
  int tid = threadIdx.x;
  float m = -1e30f, s = 0.f;
  if (tid < NTILE_N2) {
    m = part[(size_t)r * 256 + tid * 2];
    s = part[(size_t)r * 256 + tid * 2 + 1];
  }
  for (int off = 1; off < 64; off <<= 1) {
    float mo = __shfl_xor(m, off), so = __shfl_xor(s, off);
    float nm = fmaxf(m, mo);
    s = s * __expf(m - nm) + so * __expf(mo - nm);
    m = nm;
  }
  __shared__ float sm[4], ss[4], sc[1];
  if ((tid & 63) == 0) { sm[tid >> 6] = m; ss[tid >> 6] = s; }
  __syncthreads();
  if (tid == 0) {
    float mm_ = sm[0], ss_ = ss[0];
    for (int w = 1; w < 4; w++) {
      float nm = fmaxf(mm_, sm[w]);
      ss_ = ss_ * __expf(mm_ - nm) + ss[w] * __expf(sm[w] - nm);
      mm_ = nm;
    }
    sc[0] = lp[r] - (mm_ + __logf(ss_));
  }
  __syncthreads();
  float coef = sc[0];
  float4* p = (float4*)(out + (size_t)r * VOCAB + half * (VOCAB / 2));
  for (int i = tid; i < VOCAB / 8; i += 256) {
    float4 v = p[i];
    v.x += coef; v.y += coef; v.z += coef; v.w += coef;
    p[i] = v;
  }
}

// ---------------- K4s: standalone scatter (fallback path) ---------------------
__global__ __launch_bounds__(256) void k4_scatter(float* __restrict__ out,
                                                  const float* __restrict__ attn,
                                                  const int* __restrict__ enc,
                                                  const float* __restrict__ pg,
                                                  const float* __restrict__ m_a,
                                                  const float* __restrict__ s_a) {
  int idx = blockIdx.x * 256 + threadIdx.x;     // 819200
  int l = idx & (IN_LEN - 1);
  int r = idx >> 9;
  int b = r / DEC;
  float omp = 1.f - pg[r];
  if (omp <= 0.f) return;
  float term = omp * expf(attn[(size_t)r * IN_LEN + l] - m_a[r]) / s_a[r];
  int v = enc[b * IN_LEN + l];
  unsigned* ua = (unsigned*)(out + (size_t)r * VOCAB + v);
  unsigned old = *ua;
  while (true) {
    float f = __uint_as_float(old);
    float nf = logf(expf(f) + term);
    unsigned assumed = old;
    old = atomicCAS(ua, assumed, __float_as_uint(nf));
    if (old == assumed) break;
  }
}

// ======================= FALLBACK PATH (round-1 kernels) ======================
#define BM 128
#define BN 128
#define BK 32
__device__ __forceinline__ int swz_old(int row, int k) {
  int slot = (k >> 3) ^ ((row >> 1) & 3);
  return row * 32 + slot * 8 + (k & 7);
}

__global__ __launch_bounds__(256) void k2_gemm_old(const float* __restrict__ X,
                                                   const float* __restrict__ W,
                                                   const float* __restrict__ bvocab,
                                                   float* __restrict__ out) {
  __shared__ __align__(16) unsigned short As[BM * BK];
  __shared__ __align__(16) unsigned short Bs[BN * BK];
  const int mtile = blockIdx.x;
  const int ntile = blockIdx.y;
  const int tid = threadIdx.x;
  const int wid = tid >> 6, lane = tid & 63;
  const int wr = wid >> 1, wc = wid & 1;
  f32x4 acc[4][4] = {};
  float4 areg[4];
  float  breg[16];
  const int nl = tid & 127;
  const int kg = tid >> 7;
  {
#pragma unroll
    for (int i = 0; i < 4; i++) {
      int idx = tid + i * 256;
      int r = mtile * BM + (idx >> 3);
      if (r < NROW) areg[i] = *(const float4*)(X + (size_t)r * HID + (idx & 7) * 4);
      else areg[i] = make_float4(0.f, 0.f, 0.f, 0.f);
    }
    const float* base = W + (size_t)(kg * 16) * VOCAB + ntile * BN + nl;
#pragma unroll
    for (int i = 0; i < 16; i++) breg[i] = base[(size_t)i * VOCAB];
  }
  const int KS = HID / BK;
  for (int ks = 0; ks < KS; ++ks) {
#pragma unroll
    for (int i = 0; i < 4; i++) {
      int idx = tid + i * 256;
      int r = idx >> 3, kq = idx & 7;
      unsigned short w0 = f2bf(areg[i].x), w1 = f2bf(areg[i].y);
      unsigned short w2 = f2bf(areg[i].z), w3 = f2bf(areg[i].w);
      unsigned short* dstp = &As[swz_old(r, kq * 4)];
      dstp[0] = w0; dstp[1] = w1; dstp[2] = w2; dstp[3] = w3;
    }
    {
      short8 v0, v1;
#pragma unroll
      for (int i = 0; i < 8; i++) { v0[i] = (short)f2bf(breg[i]); v1[i] = (short)f2bf(breg[8 + i]); }
      *(short8*)&Bs[swz_old(nl, kg * 16)] = v0;
      *(short8*)&Bs[swz_old(nl, kg * 16 + 8)] = v1;
    }
    __syncthreads();
    if (ks + 1 < KS) {
      const int ksn = ks + 1;
#pragma unroll
      for (int i = 0; i < 4; i++) {
        int idx = tid + i * 256;
        int r = mtile * BM + (idx >> 3);
        if (r < NROW) areg[i] = *(const float4*)(X + (size_t)r * HID + ksn * BK + (idx & 7) * 4);
        else areg[i] = make_float4(0.f, 0.f, 0.f, 0.f);
      }
      const float* base = W + (size_t)(ksn * BK + kg * 16) * VOCAB + ntile * BN + nl;
#pragma unroll
      for (int i = 0; i < 16; i++) breg[i] = base[(size_t)i * VOCAB];
    }
    {
      const int k0 = (lane >> 4) * 8;
      const int rbase = wr * 64 + (lane & 15);
      const int cbase = wc * 64 + (lane & 15);
      short8 af[4], bf[4];
#pragma unroll
      for (int mm = 0; mm < 4; mm++) af[mm] = *(const short8*)&As[swz_old(rbase + mm * 16, k0)];
#pragma unroll
      for (int nn = 0; nn < 4; nn++) bf[nn] = *(const short8*)&Bs[swz_old(cbase + nn * 16, k0)];
#pragma unroll
      for (int mm = 0; mm < 4; mm++)
#pragma unroll
        for (int nn = 0; nn < 4; nn++)
          acc[mm][nn] = __builtin_amdgcn_mfma_f32_16x16x32_bf16(af[mm], bf[nn], acc[mm][nn], 0, 0, 0);
    }
    __syncthreads();
  }
#pragma unroll
  for (int mm = 0; mm < 4; mm++) {
    int row0 = mtile * BM + wr * 64 + mm * 16 + (lane >> 4) * 4;
#pragma unroll
    for (int nn = 0; nn < 4; nn++) {
      int col = ntile * BN + wc * 64 + nn * 16 + (lane & 15);
      float bb = bvocab[col];
#pragma unroll
      for (int j = 0; j < 4; j++) {
        int row = row0 + j;
        if (row < NROW) out[(size_t)row * VOCAB + col] = acc[mm][nn][j] + bb;
      }
    }
  }
}

__global__ __launch_bounds__(256) void k3_norm(float* __restrict__ out,
                                               const float* __restrict__ lp) {
  int r = blockIdx.x;
  float4* row = reinterpret_cast<float4*>(out + (size_t)r * VOCAB);
  int tid = threadIdx.x;
  float m = -1e30f, s = 0.f;
  for (int i = tid; i < VOCAB / 4; i += 256) {
    float4 v = row[i];
    float m4 = fmaxf(fmaxf(v.x, v.y), fmaxf(v.z, v.w));
    if (m4 > m) { s *= __expf(m - m4); m = m4; }
    s += __expf(v.x - m) + __expf(v.y - m) + __expf(v.z - m) + __expf(v.w - m);
  }
  for (int off = 32; off; off >>= 1) {
    float mo = __shfl_xor(m, off), so = __shfl_xor(s, off);
    float nm = fmaxf(m, mo);
    s = s * __expf(m - nm) + so * __expf(mo - nm);
    m = nm;
  }
  __shared__ float mred[4], sred[4];
  if ((tid & 63) == 0) { mred[tid >> 6] = m; sred[tid >> 6] = s; }
  __syncthreads();
  if (tid == 0) {
    float mm = mred[0], ss = sred[0];
    for (int w = 1; w < 4; w++) {
      float mo = mred[w], so = sred[w];
      float nm = fmaxf(mm, mo);
      ss = ss * __expf(mm - nm) + so * __expf(mo - nm);
      mm = nm;
    }
    mred[0] = mm; sred[0] = ss;
  }
  __syncthreads();
  m = mred[0]; s = sred[0];
  float coef = lp[r] - (m + __logf(s));
  for (int i = tid; i < VOCAB / 4; i += 256) {
    float4 v = row[i];
    v.x += coef; v.y += coef; v.z += coef; v.w += coef;
    row[i] = v;
  }
}

// -----------------------------------------------------------------------------
extern "C" void kernel_launch(void* const* d_in, const int* in_sizes, int n_in,
                              void* d_out, int out_size, void* d_ws, size_t ws_size,
                              hipStream_t stream) {
  (void)in_sizes; (void)n_in; (void)out_size;
  const float* x       = (const float*)d_in[0];
  const float* attn    = (const float*)d_in[1];
  const int*   enc_in  = (const int*)d_in[2];
  const float* enc_out = (const float*)d_in[3];
  const float* Wv      = (const float*)d_in[4];
  const float* bv      = (const float*)d_in[5];
  const float* Wg      = (const float*)d_in[6];
  const float* bg      = (const float*)d_in[7];
  float* out = (float*)d_out;
  float* ws  = (float*)d_ws;

  // ws layout (float offsets)
  float* venc = ws;                       // 8192
  float* pg   = ws + 8192;                // 1600
  float* lp   = ws + 9792;                // 1600
  float* m_a  = ws + 11392;               // 1600
  float* s_a  = ws + 12992;               // 1600
  float* part = ws + 14592;               // 1600*256 = 409600 (<=800000 reserved)
  unsigned short* Xp = (unsigned short*)(ws + 814592);    // 13*24*4096 shorts
  unsigned short* Wp = (unsigned short*)(ws + 1453568);   // 125*24*8192 shorts
  unsigned short* Lbf = (unsigned short*)(ws + 13741568); // 1600*32000 shorts
  const size_t NEED  = (size_t)13741568 * 4;              // ~55.0 MB
  const size_t NEED2 = NEED + (size_t)NROW * VOCAB * 2;   // ~157.4 MB

  hipLaunchKernelGGL(k0_venc, dim3(2048), dim3(256), 0, stream, enc_out, Wg, venc);
  hipLaunchKernelGGL(k1_row, dim3(NROW), dim3(256), 0, stream, attn, x, venc, Wg, bg,
                     pg, lp, m_a, s_a);

  if (ws_size >= NEED) {
    int use_bf = (ws_size >= NEED2) ? 1 : 0;
    hipLaunchKernelGGL(p0_pack_x, dim3(NTILE_M, KT2), dim3(256), 0, stream, x, Xp);
    hipLaunchKernelGGL(p0_pack_w, dim3(NTILE_N2, KT2), dim3(256), 0, stream, Wv, Wp);
    hipLaunchKernelGGL(k2_gemm_v6, dim3(NTILE_M * NTILE_N2), dim3(256), 0, stream,
                       Xp, Wp, bv, out, Lbf, part, use_bf);
    if (use_bf) {
      hipLaunchKernelGGL(k4_fused, dim3(NROW * 2), dim3(512), 0, stream,
                         out, Lbf, part, lp, attn, enc_in, pg, m_a, s_a);
    } else {
      hipLaunchKernelGGL(k4_finish, dim3(NROW * 2), dim3(256), 0, stream, out, part, lp);
      hipLaunchKernelGGL(k4_scatter, dim3((NROW * IN_LEN) / 256), dim3(256), 0, stream,
                         out, attn, enc_in, pg, m_a, s_a);
    }
  } else {
    hipLaunchKernelGGL(k2_gemm_old, dim3(NTILE_M, 250), dim3(256), 0, stream,
                       x, Wv, bv, out);
    hipLaunchKernelGGL(k3_norm, dim3(NROW), dim3(256), 0, stream, out, lp);
    hipLaunchKernelGGL(k4_scatter, dim3((NROW * IN_LEN) / 256), dim3(256), 0, stream,
                       out, attn, enc_in, pg, m_a, s_a);
  }
}